// Round 11
// baseline (133.205 us; speedup 1.0000x reference)
//
#include <hip/hip_runtime.h>
#include <math.h>

// Problem constants (B=4,S=4096,D=1024,F=4096,E=8,K=2)
#define DD 1024
#define FF 4096
#define NTOK 16384     // B*S
#define NPART 256      // partial sets from stats1 (one per 16-row group)
#define FIN (NPART * 5 * DD)   // finals offset in ws (floats)

// ws layout (floats):
// [0, NPART*5120)      partials: part[p][k][d], k in {sb,sd,sbb,sdd,sbd}
// [FIN, FIN+5120)      final sums (same k layout)
// [FIN+5120]           sum(bias)

// ---- DPP wave-64 sum: total broadcast to all lanes via readlane(63).
template<int CTRL, int RMASK>
__device__ __forceinline__ float dppadd(float v) {
    int m = __builtin_amdgcn_update_dpp(0, __float_as_int(v), CTRL, RMASK, 0xF, false);
    return v + __int_as_float(m);
}
__device__ __forceinline__ float wave_sum64(float v) {
    v = dppadd<0x121, 0xF>(v);   // row_ror:1
    v = dppadd<0x122, 0xF>(v);   // row_ror:2
    v = dppadd<0x124, 0xF>(v);   // row_ror:4
    v = dppadd<0x128, 0xF>(v);   // row_ror:8  -> full row-16 sums
    v = dppadd<0x142, 0xA>(v);   // row_bcast15 into rows 1,3
    v = dppadd<0x143, 0xC>(v);   // row_bcast31 into rows 2,3 -> total in lane 63
    return __int_as_float(__builtin_amdgcn_readlane(__float_as_int(v), 63));
}

// ============================================================================
// stats1: 1024 blocks (4/CU), each handles a 16-row x 256-col quarter chunk.
// Writes per-block partial sums (no atomics).
// ============================================================================
__global__ __launch_bounds__(256) void stats1_kernel(
    const float* __restrict__ Wb, const float* __restrict__ Wd,
    float* __restrict__ ws)
{
    const int tx = threadIdx.x;   // 0..63 : float4 column
    const int ty = threadIdx.y;   // 0..3  : row subgroup (one wave each)
    const int bx = blockIdx.x;    // 0..3  : col quarter
    const int by = blockIdx.y;    // 0..255: 16-row group
    const int c4 = bx * 64 + tx;  // float4 column index in [0,256)

    const float4* Wb4 = (const float4*)Wb;
    const float4* Wd4 = (const float4*)Wd;

    float4 sb  = make_float4(0.f,0.f,0.f,0.f);
    float4 sd  = sb, sbb = sb, sdd = sb, sbd = sb;

    const int row0 = by * 16 + ty * 4;
    #pragma unroll
    for (int r = 0; r < 4; ++r) {
        const int row = row0 + r;
        float4 b = Wb4[row * 256 + c4];
        float4 d = Wd4[row * 256 + c4];
        sb.x += b.x; sb.y += b.y; sb.z += b.z; sb.w += b.w;
        sd.x += d.x; sd.y += d.y; sd.z += d.z; sd.w += d.w;
        sbb.x += b.x*b.x; sbb.y += b.y*b.y; sbb.z += b.z*b.z; sbb.w += b.w*b.w;
        sdd.x += d.x*d.x; sdd.y += d.y*d.y; sdd.z += d.z*d.z; sdd.w += d.w*d.w;
        sbd.x += b.x*d.x; sbd.y += b.y*d.y; sbd.z += b.z*d.z; sbd.w += b.w*d.w;
    }

    __shared__ float4 red[4][5][64];   // 20 KB

    red[ty][0][tx] = sb;
    red[ty][1][tx] = sd;
    red[ty][2][tx] = sbb;
    red[ty][3][tx] = sdd;
    red[ty][4][tx] = sbd;
    __syncthreads();

    if (ty == 0) {
        #pragma unroll
        for (int k = 0; k < 5; ++k) {
            float4 acc = red[0][k][tx];
            #pragma unroll
            for (int g = 1; g < 4; ++g) {
                float4 a = red[g][k][tx];
                acc.x += a.x; acc.y += a.y; acc.z += a.z; acc.w += a.w;
            }
            ((float4*)(ws + by * (5 * DD) + k * DD))[c4] = acc;
        }
    }
}

// ============================================================================
// stats2: 80 blocks x 256 thr. Block handles 16 float4-cols of the FLAT
// 5120-float space (fully coalesced); thread = (slice, col), slice sums 16
// partials, LDS tree across 16 slices. Bias in block 0.
// ============================================================================
__global__ __launch_bounds__(256) void stats2_kernel(
    const float* __restrict__ bias, float* __restrict__ ws)
{
    const int tid   = threadIdx.x;
    const int col   = tid & 15;          // 0..15 within block's 16 cols
    const int slice = tid >> 4;          // 0..15 partial slice
    const int c4    = blockIdx.x * 16 + col;   // float4 column in [0,1280)

    const float4* p4 = (const float4*)ws;
    float4 acc = make_float4(0.f,0.f,0.f,0.f);
    #pragma unroll 4
    for (int p = slice * 16; p < slice * 16 + 16; ++p) {
        float4 a = p4[(size_t)p * 1280 + c4];
        acc.x += a.x; acc.y += a.y; acc.z += a.z; acc.w += a.w;
    }

    __shared__ float4 red[16][17];   // +1 pad
    red[slice][col] = acc;
    __syncthreads();

    if (slice == 0) {
        float4 a = red[0][col];
        #pragma unroll
        for (int s = 1; s < 16; ++s) {
            float4 b = red[s][col];
            a.x += b.x; a.y += b.y; a.z += b.z; a.w += b.w;
        }
        ((float4*)(ws + FIN))[c4] = a;
    }

    if (blockIdx.x == 0) {
        float s = 0.f;
        #pragma unroll
        for (int i = 0; i < 16; ++i) s += bias[tid + 256 * i];
        #pragma unroll
        for (int off = 32; off > 0; off >>= 1) s += __shfl_xor(s, off);
        __shared__ float bws[4];
        if ((tid & 63) == 0) bws[tid >> 6] = s;
        __syncthreads();
        if (tid == 0) ws[FIN + 5120] = bws[0] + bws[1] + bws[2] + bws[3];
    }
}

__device__ __forceinline__ float sel2(int t, float a, float b) {
    return t ? b : a;
}

// ============================================================================
// router: 2048 blocks (8/CU, verified best occupancy), 2 tokens/wave.
// CHANGE vs R10: ALL 8 x-float4 loads issued up front (no mid-loop refills /
// vmcnt waits); staging + barrier hide the latency; compiler sinks late loads
// if the 64-VGPR budget demands it.
// ============================================================================
__global__ __launch_bounds__(256, 8) void router_kernel(
    const float* __restrict__ x,
    const float* __restrict__ alpha, const float* __restrict__ beta,
    const float* __restrict__ ws, float* __restrict__ out)
{
    __shared__ float4 smem[1280];   // 20 KB
    float4* s_mb4 = smem;
    float4* s_md4 = smem + 256;
    float4* s_vb4 = smem + 512;
    float4* s_vd4 = smem + 768;
    float4* s_cb4 = smem + 1024;
    float* s_mb = (float*)s_mb4;
    float* s_md = (float*)s_md4;
    float* s_vb = (float*)s_vb4;
    float* s_vd = (float*)s_vd4;
    float* s_cb = (float*)s_cb4;

    const int tid  = threadIdx.x;
    const int lane = tid & 63;
    const int wave = tid >> 6;
    const int gw   = blockIdx.x * 4 + wave;   // global wave id, [0,8192)
    const int tok0 = gw * 2;

    const float4* xr = (const float4*)(x) + (size_t)tok0 * 256;

    // ---- issue ALL 8 x loads up front, it-major (consumption order)
    float4 xv[8];
    #pragma unroll
    for (int it = 0; it < 4; ++it) {
        #pragma unroll
        for (int t = 0; t < 2; ++t)
            xv[it * 2 + t] = xr[t * 256 + it * 64 + lane];
    }

    const float invF = 1.0f / (float)FF;
    const float* fin = ws + FIN;

    for (int i = tid; i < DD; i += 256) {
        float sb  = fin[i];
        float sd  = fin[DD + i];
        float sbb = fin[2 * DD + i];
        float sdd = fin[3 * DD + i];
        float sbd = fin[4 * DD + i];
        float mb = sb * invF, md = sd * invF;
        s_mb[i] = mb;
        s_md[i] = md;
        s_vb[i] = fmaxf(sbb * invF - mb * mb, 0.f);
        s_vd[i] = fmaxf(sdd * invF - md * md, 0.f);
        s_cb[i] = sbd * invF - mb * md;
    }
    const float bias_mean = fin[5120] * invF;
    __syncthreads();

    float s1[2], s2[2], t1[2], t2[2], t3[2];
    #pragma unroll
    for (int t = 0; t < 2; ++t) { s1[t]=0.f; s2[t]=0.f; t1[t]=0.f; t2[t]=0.f; t3[t]=0.f; }

    #pragma unroll
    for (int it = 0; it < 4; ++it) {
        const int i4 = it * 64 + lane;
        const float4 mb = s_mb4[i4];
        const float4 md = s_md4[i4];
        const float4 vb = s_vb4[i4];
        const float4 vd = s_vd4[i4];
        const float4 cb = s_cb4[i4];
        #pragma unroll
        for (int t = 0; t < 2; ++t) {
            float4 xvv = xv[it * 2 + t];
            float x2x = xvv.x*xvv.x, x2y = xvv.y*xvv.y, x2z = xvv.z*xvv.z, x2w = xvv.w*xvv.w;
            s1[t] += xvv.x*mb.x + xvv.y*mb.y + xvv.z*mb.z + xvv.w*mb.w;
            s2[t] += xvv.x*md.x + xvv.y*md.y + xvv.z*md.z + xvv.w*md.w;
            t1[t] += x2x*vb.x + x2y*vb.y + x2z*vb.z + x2w*vb.w;
            t2[t] += x2x*vd.x + x2y*vd.y + x2z*vd.z + x2w*vd.w;
            t3[t] += x2x*cb.x + x2y*cb.y + x2z*cb.z + x2w*cb.w;
        }
    }

    // ---- DPP wave reductions: 10 wave-uniform sums
    float A1[2], A2[2], B1[2], B2[2], B3[2];
    #pragma unroll
    for (int t = 0; t < 2; ++t) {
        A1[t] = wave_sum64(s1[t]);
        A2[t] = wave_sum64(s2[t]);
        B1[t] = wave_sum64(t1[t]);
        B2[t] = wave_sum64(t2[t]);
        B3[t] = wave_sum64(t3[t]);
    }

    // ---- lanes 0..15: token tt = (lane>>3)&1, expert e = lane&7
    const int tt = (lane >> 3) & 1;
    const int e  = lane & 7;
    const float a_e = alpha[e];
    const float b_e = beta[e];

    float S1 = sel2(tt, A1[0], A1[1]);
    float S2 = sel2(tt, A2[0], A2[1]);
    float T1 = sel2(tt, B1[0], B1[1]);
    float T2 = sel2(tt, B2[0], B2[1]);
    float T3 = sel2(tt, B3[0], B3[1]);

    float mu  = a_e * S1 + b_e * S2 + bias_mean;
    float var = a_e * a_e * T1 + b_e * b_e * T2 + 2.f * a_e * b_e * T3;
    float z   = mu / sqrtf(2.f * (var + 1e-8f));
    float logit = erff(z);

    // gather the 8 expert logits of this lane's token
    const int base = lane & 56;   // lanes<16 -> 0 or 8
    float l[8];
    #pragma unroll
    for (int q = 0; q < 8; ++q) l[q] = __shfl(logit, base + q);

    // top-2, tie-break = first index (matches lax.top_k)
    float vmax = l[0]; int i0 = 0;
    #pragma unroll
    for (int q = 1; q < 8; ++q) { if (l[q] > vmax) { vmax = l[q]; i0 = q; } }
    float vsec = -1e30f; int i1 = 0;
    #pragma unroll
    for (int q = 0; q < 8; ++q) { if (q != i0 && l[q] > vsec) { vsec = l[q]; i1 = q; } }

    float e1  = __expf(vsec - vmax);
    float inv = 1.f / (1.f + e1);
    float wtop = inv, wsec = e1 * inv;

    if (lane < 16) {
        const int token = tok0 + tt;
        float w = (e == i0) ? wtop : ((e == i1) ? wsec : 0.f);
        out[(size_t)token * 8 + e] = w;
        out[(size_t)NTOK * 8 + (size_t)token * 8 + e] = logit;
    }
}

extern "C" void kernel_launch(void* const* d_in, const int* in_sizes, int n_in,
                              void* d_out, int out_size, void* d_ws, size_t ws_size,
                              hipStream_t stream)
{
    const float* x     = (const float*)d_in[0];
    const float* Wb    = (const float*)d_in[1];
    const float* Wd    = (const float*)d_in[2];
    const float* bias  = (const float*)d_in[3];
    const float* alpha = (const float*)d_in[4];
    const float* beta  = (const float*)d_in[5];
    float* out = (float*)d_out;
    float* ws  = (float*)d_ws;

    dim3 b1(64, 4), g1(4, 256);
    stats1_kernel<<<g1, b1, 0, stream>>>(Wb, Wd, ws);

    stats2_kernel<<<80, 256, 0, stream>>>(bias, ws);

    router_kernel<<<2048, 256, 0, stream>>>(x, alpha, beta, ws, out);
}

// Round 12
// 129.717 us; speedup vs baseline: 1.0269x; 1.0269x over previous
//
#include <hip/hip_runtime.h>
#include <math.h>

// Problem constants (B=4,S=4096,D=1024,F=4096,E=8,K=2)
#define DD 1024
#define FF 4096
#define NTOK 16384     // B*S
#define NPART 256      // partial sets from stats1 (one per 16-row group)
#define FIN (NPART * 5 * DD)   // finals offset in ws (floats)

// ws layout (floats):
// [0, NPART*5120)      partials: part[p][k][d], k in {sb,sd,sbb,sdd,sbd}
// [FIN, FIN+5120)      final sums (same k layout)
// [FIN+5120]           sum(bias)

// ---- DPP wave-64 sum: total broadcast to all lanes via readlane(63).
template<int CTRL, int RMASK>
__device__ __forceinline__ float dppadd(float v) {
    int m = __builtin_amdgcn_update_dpp(0, __float_as_int(v), CTRL, RMASK, 0xF, false);
    return v + __int_as_float(m);
}
__device__ __forceinline__ float wave_sum64(float v) {
    v = dppadd<0x121, 0xF>(v);   // row_ror:1
    v = dppadd<0x122, 0xF>(v);   // row_ror:2
    v = dppadd<0x124, 0xF>(v);   // row_ror:4
    v = dppadd<0x128, 0xF>(v);   // row_ror:8  -> full row-16 sums
    v = dppadd<0x142, 0xA>(v);   // row_bcast15 into rows 1,3
    v = dppadd<0x143, 0xC>(v);   // row_bcast31 into rows 2,3 -> total in lane 63
    return __int_as_float(__builtin_amdgcn_readlane(__float_as_int(v), 63));
}

// ============================================================================
// stats1: 1024 blocks (4/CU), each handles a 16-row x 256-col quarter chunk.
// Writes per-block partial sums (no atomics).
// ============================================================================
__global__ __launch_bounds__(256) void stats1_kernel(
    const float* __restrict__ Wb, const float* __restrict__ Wd,
    float* __restrict__ ws)
{
    const int tx = threadIdx.x;   // 0..63 : float4 column
    const int ty = threadIdx.y;   // 0..3  : row subgroup (one wave each)
    const int bx = blockIdx.x;    // 0..3  : col quarter
    const int by = blockIdx.y;    // 0..255: 16-row group
    const int c4 = bx * 64 + tx;  // float4 column index in [0,256)

    const float4* Wb4 = (const float4*)Wb;
    const float4* Wd4 = (const float4*)Wd;

    float4 sb  = make_float4(0.f,0.f,0.f,0.f);
    float4 sd  = sb, sbb = sb, sdd = sb, sbd = sb;

    const int row0 = by * 16 + ty * 4;
    #pragma unroll
    for (int r = 0; r < 4; ++r) {
        const int row = row0 + r;
        float4 b = Wb4[row * 256 + c4];
        float4 d = Wd4[row * 256 + c4];
        sb.x += b.x; sb.y += b.y; sb.z += b.z; sb.w += b.w;
        sd.x += d.x; sd.y += d.y; sd.z += d.z; sd.w += d.w;
        sbb.x += b.x*b.x; sbb.y += b.y*b.y; sbb.z += b.z*b.z; sbb.w += b.w*b.w;
        sdd.x += d.x*d.x; sdd.y += d.y*d.y; sdd.z += d.z*d.z; sdd.w += d.w*d.w;
        sbd.x += b.x*d.x; sbd.y += b.y*d.y; sbd.z += b.z*d.z; sbd.w += b.w*d.w;
    }

    __shared__ float4 red[4][5][64];   // 20 KB

    red[ty][0][tx] = sb;
    red[ty][1][tx] = sd;
    red[ty][2][tx] = sbb;
    red[ty][3][tx] = sdd;
    red[ty][4][tx] = sbd;
    __syncthreads();

    if (ty == 0) {
        #pragma unroll
        for (int k = 0; k < 5; ++k) {
            float4 acc = red[0][k][tx];
            #pragma unroll
            for (int g = 1; g < 4; ++g) {
                float4 a = red[g][k][tx];
                acc.x += a.x; acc.y += a.y; acc.z += a.z; acc.w += a.w;
            }
            ((float4*)(ws + by * (5 * DD) + k * DD))[c4] = acc;
        }
    }
}

// ============================================================================
// stats2: 80 blocks x 256 thr. Block handles 16 float4-cols of the FLAT
// 5120-float space (fully coalesced); thread = (slice, col), slice sums 16
// partials, LDS tree across 16 slices. Bias in block 0.
// ============================================================================
__global__ __launch_bounds__(256) void stats2_kernel(
    const float* __restrict__ bias, float* __restrict__ ws)
{
    const int tid   = threadIdx.x;
    const int col   = tid & 15;          // 0..15 within block's 16 cols
    const int slice = tid >> 4;          // 0..15 partial slice
    const int c4    = blockIdx.x * 16 + col;   // float4 column in [0,1280)

    const float4* p4 = (const float4*)ws;
    float4 acc = make_float4(0.f,0.f,0.f,0.f);
    #pragma unroll 4
    for (int p = slice * 16; p < slice * 16 + 16; ++p) {
        float4 a = p4[(size_t)p * 1280 + c4];
        acc.x += a.x; acc.y += a.y; acc.z += a.z; acc.w += a.w;
    }

    __shared__ float4 red[16][17];   // +1 pad
    red[slice][col] = acc;
    __syncthreads();

    if (slice == 0) {
        float4 a = red[0][col];
        #pragma unroll
        for (int s = 1; s < 16; ++s) {
            float4 b = red[s][col];
            a.x += b.x; a.y += b.y; a.z += b.z; a.w += b.w;
        }
        ((float4*)(ws + FIN))[c4] = a;
    }

    if (blockIdx.x == 0) {
        float s = 0.f;
        #pragma unroll
        for (int i = 0; i < 16; ++i) s += bias[tid + 256 * i];
        #pragma unroll
        for (int off = 32; off > 0; off >>= 1) s += __shfl_xor(s, off);
        __shared__ float bws[4];
        if ((tid & 63) == 0) bws[tid >> 6] = s;
        __syncthreads();
        if (tid == 0) ws[FIN + 5120] = bws[0] + bws[1] + bws[2] + bws[3];
    }
}

__device__ __forceinline__ float sel2(int t, float a, float b) {
    return t ? b : a;
}

// ============================================================================
// router (verified-best config, 130.5/130.8us): 2048 blocks (8/CU), 2 tokens
// per wave, 2-deep software pipeline on x loads, LDS staging with in-staging
// normalization (hidden under x-prefetch latency). launch_bounds(256,8).
// ============================================================================
__global__ __launch_bounds__(256, 8) void router_kernel(
    const float* __restrict__ x,
    const float* __restrict__ alpha, const float* __restrict__ beta,
    const float* __restrict__ ws, float* __restrict__ out)
{
    __shared__ float4 smem[1280];   // 20 KB
    float4* s_mb4 = smem;
    float4* s_md4 = smem + 256;
    float4* s_vb4 = smem + 512;
    float4* s_vd4 = smem + 768;
    float4* s_cb4 = smem + 1024;
    float* s_mb = (float*)s_mb4;
    float* s_md = (float*)s_md4;
    float* s_vb = (float*)s_vb4;
    float* s_vd = (float*)s_vd4;
    float* s_cb = (float*)s_cb4;

    const int tid  = threadIdx.x;
    const int lane = tid & 63;
    const int wave = tid >> 6;
    const int gw   = blockIdx.x * 4 + wave;   // global wave id, [0,8192)
    const int tok0 = gw * 2;

    const float4* xr = (const float4*)(x) + (size_t)tok0 * 256;

    // ---- preload pipeline stages it=0, it=1 (2 tokens each) before staging:
    //      their HBM latency hides under the staging loads + barrier.
    float4 xp0[2], xp1[2];
    #pragma unroll
    for (int t = 0; t < 2; ++t) xp0[t] = xr[t * 256 + 0 * 64 + lane];
    #pragma unroll
    for (int t = 0; t < 2; ++t) xp1[t] = xr[t * 256 + 1 * 64 + lane];

    const float invF = 1.0f / (float)FF;
    const float* fin = ws + FIN;

    for (int i = tid; i < DD; i += 256) {
        float sb  = fin[i];
        float sd  = fin[DD + i];
        float sbb = fin[2 * DD + i];
        float sdd = fin[3 * DD + i];
        float sbd = fin[4 * DD + i];
        float mb = sb * invF, md = sd * invF;
        s_mb[i] = mb;
        s_md[i] = md;
        s_vb[i] = fmaxf(sbb * invF - mb * mb, 0.f);
        s_vd[i] = fmaxf(sdd * invF - md * md, 0.f);
        s_cb[i] = sbd * invF - mb * md;
    }
    const float bias_mean = fin[5120] * invF;
    __syncthreads();

    float s1[2], s2[2], t1[2], t2[2], t3[2];
    #pragma unroll
    for (int t = 0; t < 2; ++t) { s1[t]=0.f; s2[t]=0.f; t1[t]=0.f; t2[t]=0.f; t3[t]=0.f; }

    #pragma unroll
    for (int it = 0; it < 4; ++it) {
        const int i4 = it * 64 + lane;
        const float4 mb = s_mb4[i4];
        const float4 md = s_md4[i4];
        const float4 vb = s_vb4[i4];
        const float4 vd = s_vd4[i4];
        const float4 cb = s_cb4[i4];
        #pragma unroll
        for (int t = 0; t < 2; ++t) {
            float4 xv = (it & 1) ? xp1[t] : xp0[t];
            float x2x = xv.x*xv.x, x2y = xv.y*xv.y, x2z = xv.z*xv.z, x2w = xv.w*xv.w;
            s1[t] += xv.x*mb.x + xv.y*mb.y + xv.z*mb.z + xv.w*mb.w;
            s2[t] += xv.x*md.x + xv.y*md.y + xv.z*md.z + xv.w*md.w;
            t1[t] += x2x*vb.x + x2y*vb.y + x2z*vb.z + x2w*vb.w;
            t2[t] += x2x*vd.x + x2y*vd.y + x2z*vd.z + x2w*vd.w;
            t3[t] += x2x*cb.x + x2y*cb.y + x2z*cb.z + x2w*cb.w;
        }
        // refill the just-consumed stage with it+2 (2-deep lookahead)
        if (it < 2) {
            #pragma unroll
            for (int t = 0; t < 2; ++t) {
                float4 nv = xr[t * 256 + (it + 2) * 64 + lane];
                if (it & 1) xp1[t] = nv; else xp0[t] = nv;
            }
        }
    }

    // ---- DPP wave reductions: 10 wave-uniform sums
    float A1[2], A2[2], B1[2], B2[2], B3[2];
    #pragma unroll
    for (int t = 0; t < 2; ++t) {
        A1[t] = wave_sum64(s1[t]);
        A2[t] = wave_sum64(s2[t]);
        B1[t] = wave_sum64(t1[t]);
        B2[t] = wave_sum64(t2[t]);
        B3[t] = wave_sum64(t3[t]);
    }

    // ---- lanes 0..15: token tt = (lane>>3)&1, expert e = lane&7
    const int tt = (lane >> 3) & 1;
    const int e  = lane & 7;
    const float a_e = alpha[e];
    const float b_e = beta[e];

    float S1 = sel2(tt, A1[0], A1[1]);
    float S2 = sel2(tt, A2[0], A2[1]);
    float T1 = sel2(tt, B1[0], B1[1]);
    float T2 = sel2(tt, B2[0], B2[1]);
    float T3 = sel2(tt, B3[0], B3[1]);

    float mu  = a_e * S1 + b_e * S2 + bias_mean;
    float var = a_e * a_e * T1 + b_e * b_e * T2 + 2.f * a_e * b_e * T3;
    float z   = mu / sqrtf(2.f * (var + 1e-8f));
    float logit = erff(z);

    // gather the 8 expert logits of this lane's token
    const int base = lane & 56;   // lanes<16 -> 0 or 8
    float l[8];
    #pragma unroll
    for (int q = 0; q < 8; ++q) l[q] = __shfl(logit, base + q);

    // top-2, tie-break = first index (matches lax.top_k)
    float vmax = l[0]; int i0 = 0;
    #pragma unroll
    for (int q = 1; q < 8; ++q) { if (l[q] > vmax) { vmax = l[q]; i0 = q; } }
    float vsec = -1e30f; int i1 = 0;
    #pragma unroll
    for (int q = 0; q < 8; ++q) { if (q != i0 && l[q] > vsec) { vsec = l[q]; i1 = q; } }

    float e1  = __expf(vsec - vmax);
    float inv = 1.f / (1.f + e1);
    float wtop = inv, wsec = e1 * inv;

    if (lane < 16) {
        const int token = tok0 + tt;
        float w = (e == i0) ? wtop : ((e == i1) ? wsec : 0.f);
        out[(size_t)token * 8 + e] = w;
        out[(size_t)NTOK * 8 + (size_t)token * 8 + e] = logit;
    }
}

extern "C" void kernel_launch(void* const* d_in, const int* in_sizes, int n_in,
                              void* d_out, int out_size, void* d_ws, size_t ws_size,
                              hipStream_t stream)
{
    const float* x     = (const float*)d_in[0];
    const float* Wb    = (const float*)d_in[1];
    const float* Wd    = (const float*)d_in[2];
    const float* bias  = (const float*)d_in[3];
    const float* alpha = (const float*)d_in[4];
    const float* beta  = (const float*)d_in[5];
    float* out = (float*)d_out;
    float* ws  = (float*)d_ws;

    dim3 b1(64, 4), g1(4, 256);
    stats1_kernel<<<g1, b1, 0, stream>>>(Wb, Wd, ws);

    stats2_kernel<<<80, 256, 0, stream>>>(bias, ws);

    router_kernel<<<2048, 256, 0, stream>>>(x, alpha, beta, ws, out);
}